// Round 1
// baseline (1920.438 us; speedup 1.0000x reference)
//
#include <hip/hip_runtime.h>
#include <hip/hip_bf16.h>

#define BLK 256

// ---------------------------------------------------------------------------
// GCN pipeline, restructured:
//   dinv[v] = rsqrt(indeg[v] + 1)
//   h1s[v]  = (x[v] @ W1) * dinv[v]                 (gemm1_k, also inits agg1)
//   agg1[v] = h1s[v] + sum_{e: dst=v} h1s[src_e]    (edge_agg_k, atomics)
//   z1s[v]  = relu(agg1[v]*dinv[v] + b1) * dinv[v]  (z1_k, also inits agg2)
//   agg2[v] = z1s[v] + sum_{e: dst=v} z1s[src_e]    (edge_agg_k, atomics)
//   out[v]  = log_softmax( (agg2[v]*dinv[v]) @ W2 + b2 )   (final_k)
// Layer-2 aggregation is done on 16 channels (pre-W2) — 4x less edge traffic.
// ---------------------------------------------------------------------------

__global__ __launch_bounds__(BLK)
void deg_count_k(const int* __restrict__ dst, unsigned* __restrict__ cnt, int E) {
    int e = blockIdx.x * BLK + threadIdx.x;
    if (e < E) atomicAdd(&cnt[dst[e]], 1u);
}

__global__ __launch_bounds__(BLK)
void dinv_k(const unsigned* __restrict__ cnt, float* __restrict__ dinv, int N) {
    int v = blockIdx.x * BLK + threadIdx.x;
    if (v < N) dinv[v] = rsqrtf((float)cnt[v] + 1.0f);
}

// h1s[v][c] = (x[v] @ W1[:,c]) * dinv[v]; also agg1 = h1s (self-loop init).
// 16 threads per row (c = t&15); x read as float4 (broadcast across the 16),
// W1 scalar reads are 64B-coalesced across c and L1-resident (32 KB).
__global__ __launch_bounds__(BLK)
void gemm1_k(const float* __restrict__ x, const float* __restrict__ W1,
             const float* __restrict__ dinv, float* __restrict__ h1s,
             float* __restrict__ agg1, int N) {
    int t = blockIdx.x * BLK + threadIdx.x;
    int v = t >> 4, c = t & 15;
    if (v >= N) return;
    const float4* xr = (const float4*)(x + (size_t)v * 512);
    float acc = 0.f;
#pragma unroll 8
    for (int i = 0; i < 128; ++i) {
        float4 a = xr[i];
        const float* wr = W1 + i * 64 + c;   // W1[(4i)][c], row-major [512][16]
        acc = fmaf(a.x, wr[0],  acc);
        acc = fmaf(a.y, wr[16], acc);
        acc = fmaf(a.z, wr[32], acc);
        acc = fmaf(a.w, wr[48], acc);
    }
    float val = acc * dinv[v];
    h1s[t]  = val;
    agg1[t] = val;
}

// agg[dst] += hs[src], 16 channels; 4 threads per edge, float4 gather,
// native fp32 atomics (unsafeAtomicAdd -> global_atomic_add_f32).
__global__ __launch_bounds__(BLK)
void edge_agg_k(const int* __restrict__ src, const int* __restrict__ dst,
                const float* __restrict__ hs, float* __restrict__ agg, int E) {
    int t = blockIdx.x * BLK + threadIdx.x;
    if (t >= E * 4) return;
    int e = t >> 2, q = t & 3;
    int s = src[e], d = dst[e];
    float4 val = ((const float4*)hs)[s * 4 + q];
    float* ap = agg + (size_t)d * 16 + q * 4;
    unsafeAtomicAdd(ap + 0, val.x);
    unsafeAtomicAdd(ap + 1, val.y);
    unsafeAtomicAdd(ap + 2, val.z);
    unsafeAtomicAdd(ap + 3, val.w);
}

// z1s[v][c] = relu(agg1[v][c]*dinv[v] + b1[c]) * dinv[v]; also agg2 = z1s.
__global__ __launch_bounds__(BLK)
void z1_k(const float* __restrict__ agg1, const float* __restrict__ dinv,
          const float* __restrict__ b1, float* __restrict__ z1s,
          float* __restrict__ agg2, int N) {
    int t = blockIdx.x * BLK + threadIdx.x;
    if (t >= N * 16) return;
    int v = t >> 4, c = t & 15;
    float s = dinv[v];
    float val = fmaxf(fmaf(agg1[t], s, b1[c]), 0.f) * s;
    z1s[t]  = val;
    agg2[t] = val;
}

// out[v] = log_softmax( (agg2[v]*dinv[v]) @ W2 + b2 ), one wave per node,
// lane = output channel (64). W2 (4 KB) staged in LDS.
__global__ __launch_bounds__(BLK)
void final_k(const float* __restrict__ agg2, const float* __restrict__ dinv,
             const float* __restrict__ W2, const float* __restrict__ b2,
             float* __restrict__ out, int N) {
    __shared__ float w2s[1024];
    __shared__ float b2s[64];
    int tid = threadIdx.x;
    for (int i = tid; i < 1024; i += BLK) w2s[i] = W2[i];
    if (tid < 64) b2s[tid] = b2[tid];
    __syncthreads();
    int v = blockIdx.x * 4 + (tid >> 6);
    int lane = tid & 63;
    if (v >= N) return;
    float s = dinv[v];
    float wv = agg2[(size_t)v * 16 + (lane & 15)] * s;   // lanes 0-15 hold w[0..15]
    float acc = b2s[lane];
#pragma unroll
    for (int k = 0; k < 16; ++k) {
        float wk = __shfl(wv, k, 64);
        acc = fmaf(wk, w2s[k * 64 + lane], acc);
    }
    // log-softmax across 64 lanes
    float m = acc;
#pragma unroll
    for (int off = 32; off; off >>= 1) m = fmaxf(m, __shfl_xor(m, off, 64));
    float p = __expf(acc - m);
#pragma unroll
    for (int off = 32; off; off >>= 1) p += __shfl_xor(p, off, 64);
    out[(size_t)v * 64 + lane] = acc - m - __logf(p);
}

extern "C" void kernel_launch(void* const* d_in, const int* in_sizes, int n_in,
                              void* d_out, int out_size, void* d_ws, size_t ws_size,
                              hipStream_t stream) {
    const float* x  = (const float*)d_in[0];
    const int*   ei = (const int*)d_in[1];     // int64 in ref -> staged as int32
    const float* W1 = (const float*)d_in[2];
    const float* b1 = (const float*)d_in[3];
    const float* W2 = (const float*)d_in[4];
    const float* b2 = (const float*)d_in[5];
    float* out = (float*)d_out;

    int hid   = in_sizes[3];                   // 16
    int in_ch = in_sizes[2] / hid;             // 512
    int E     = in_sizes[1] / 2;               // 3.2M
    int N     = in_sizes[0] / in_ch;           // 100000
    const int* src = ei;
    const int* dst = ei + E;

    char* w = (char*)d_ws;
    size_t off = 0;
    auto alloc = [&](size_t bytes) -> void* {
        void* p = w + off;
        off += (bytes + 255) & ~(size_t)255;
        return p;
    };
    unsigned* cnt  = (unsigned*)alloc((size_t)N * 4);
    float*    dinv = (float*)alloc((size_t)N * 4);
    float*    h1s  = (float*)alloc((size_t)N * 64);
    float*    agg1 = (float*)alloc((size_t)N * 64);
    float*    z1s  = (float*)alloc((size_t)N * 64);
    float*    agg2 = (float*)alloc((size_t)N * 64);

    hipMemsetAsync(cnt, 0, (size_t)N * 4, stream);
    deg_count_k<<<(E + BLK - 1) / BLK, BLK, 0, stream>>>(dst, cnt, E);
    dinv_k<<<(N + BLK - 1) / BLK, BLK, 0, stream>>>(cnt, dinv, N);
    gemm1_k<<<(N * 16 + BLK - 1) / BLK, BLK, 0, stream>>>(x, W1, dinv, h1s, agg1, N);
    edge_agg_k<<<(E * 4 + BLK - 1) / BLK, BLK, 0, stream>>>(src, dst, h1s, agg1, E);
    z1_k<<<(N * 16 + BLK - 1) / BLK, BLK, 0, stream>>>(agg1, dinv, b1, z1s, agg2, N);
    edge_agg_k<<<(E * 4 + BLK - 1) / BLK, BLK, 0, stream>>>(src, dst, z1s, agg2, E);
    final_k<<<(N + 3) / 4, BLK, 0, stream>>>(agg2, dinv, W2, b2, out, N);
}

// Round 2
// 1308.490 us; speedup vs baseline: 1.4677x; 1.4677x over previous
//
#include <hip/hip_runtime.h>
#include <hip/hip_bf16.h>

#define BLK 256
#define CHUNK 8192          // edges per binning block
#define NPB 128             // nodes per bin (LDS accum = 128*16*4 = 8KB)

// ---------------------------------------------------------------------------
// GCN, atomic-free aggregation via destination binning:
//   bin edges by dst>>7 once (count/scan/scatter, packed src|ldst<<17)
//   dinv from binned edges (LDS counters)
//   h1s = (x@W1)*dinv
//   bin_agg1: LDS-accumulate h1s[src] per bin; fused epilogue ->
//             z1s = relu((h1s + agg)*dinv + b1)*dinv
//   bin_agg2: LDS-accumulate z1s[src] per bin; fused epilogue ->
//             out = log_softmax(((z1s + agg)*dinv) @ W2 + b2)
// ---------------------------------------------------------------------------

__global__ __launch_bounds__(BLK)
void bin_count_k(const int* __restrict__ dst, int E,
                 int nbins, unsigned* __restrict__ binCnt) {
    __shared__ unsigned h[1024];
    for (int i = threadIdx.x; i < 1024; i += BLK) h[i] = 0u;
    __syncthreads();
    int base = blockIdx.x * CHUNK;
    int end  = min(base + CHUNK, E);
    for (int e = base + threadIdx.x; e < end; e += BLK)
        atomicAdd(&h[dst[e] >> 7], 1u);
    __syncthreads();
    for (int i = threadIdx.x; i < nbins; i += BLK)
        if (h[i]) atomicAdd(&binCnt[i], h[i]);
}

// single block, 1024 threads: exclusive scan of binCnt -> binBase, binCursor
__global__ __launch_bounds__(1024)
void scan_k(const unsigned* __restrict__ binCnt, int nbins,
            unsigned* __restrict__ binBase, unsigned* __restrict__ binCursor) {
    __shared__ unsigned s[1024];
    int t = threadIdx.x;
    unsigned v = (t < nbins) ? binCnt[t] : 0u;
    s[t] = v;
    __syncthreads();
    for (int off = 1; off < 1024; off <<= 1) {
        unsigned add = (t >= off) ? s[t - off] : 0u;
        __syncthreads();
        s[t] += add;
        __syncthreads();
    }
    if (t < nbins) {
        unsigned excl = s[t] - v;
        binBase[t]   = excl;
        binCursor[t] = excl;
    }
}

__global__ __launch_bounds__(BLK)
void scatter_k(const int* __restrict__ src, const int* __restrict__ dst, int E,
               int nbins, unsigned* __restrict__ binCursor,
               unsigned* __restrict__ packed) {
    __shared__ unsigned h[1024];
    __shared__ unsigned cur[1024];
    for (int i = threadIdx.x; i < 1024; i += BLK) h[i] = 0u;
    __syncthreads();
    int base = blockIdx.x * CHUNK;
    int end  = min(base + CHUNK, E);
    for (int e = base + threadIdx.x; e < end; e += BLK)
        atomicAdd(&h[dst[e] >> 7], 1u);
    __syncthreads();
    for (int i = threadIdx.x; i < nbins; i += BLK)
        cur[i] = h[i] ? atomicAdd(&binCursor[i], h[i]) : 0u;
    __syncthreads();
    for (int e = base + threadIdx.x; e < end; e += BLK) {
        int d = dst[e];
        unsigned pos = atomicAdd(&cur[d >> 7], 1u);
        packed[pos] = (unsigned)src[e] | ((unsigned)(d & (NPB - 1)) << 17);
    }
}

__global__ __launch_bounds__(BLK)
void bin_dinv_k(const unsigned* __restrict__ packed,
                const unsigned* __restrict__ binBase,
                const unsigned* __restrict__ binCnt,
                float* __restrict__ dinv, int N) {
    __shared__ unsigned cnt[NPB];
    int b = blockIdx.x, tid = threadIdx.x;
    int vbase = b << 7;
    if (vbase >= N) return;
    if (tid < NPB) cnt[tid] = 0u;
    __syncthreads();
    unsigned s0 = binBase[b], n = binCnt[b];
    for (unsigned i = tid; i < n; i += BLK)
        atomicAdd(&cnt[packed[s0 + i] >> 17], 1u);
    __syncthreads();
    int v = vbase + tid;
    if (tid < NPB && v < N)
        dinv[v] = rsqrtf((float)cnt[tid] + 1.0f);
}

// h1s[v][c] = (x[v] @ W1[:,c]) * dinv[v]; 16 threads per node row.
__global__ __launch_bounds__(BLK)
void gemm1_k(const float* __restrict__ x, const float* __restrict__ W1,
             const float* __restrict__ dinv, float* __restrict__ h1s, int N) {
    int t = blockIdx.x * BLK + threadIdx.x;
    int v = t >> 4, c = t & 15;
    if (v >= N) return;
    const float4* xr = (const float4*)(x + (size_t)v * 512);
    float acc = 0.f;
#pragma unroll 8
    for (int i = 0; i < 128; ++i) {
        float4 a = xr[i];
        const float* wr = W1 + i * 64 + c;
        acc = fmaf(a.x, wr[0],  acc);
        acc = fmaf(a.y, wr[16], acc);
        acc = fmaf(a.z, wr[32], acc);
        acc = fmaf(a.w, wr[48], acc);
    }
    h1s[t] = acc * dinv[v];
}

// Bin-local aggregation of h1s into LDS, fused relu/bias epilogue -> z1s.
__global__ __launch_bounds__(BLK)
void bin_agg1_k(const unsigned* __restrict__ packed,
                const unsigned* __restrict__ binBase,
                const unsigned* __restrict__ binCnt,
                const float* __restrict__ h1s, const float* __restrict__ dinv,
                const float* __restrict__ b1, float* __restrict__ z1s, int N) {
    __shared__ float acc[NPB * 16];     // 8 KB
    int b = blockIdx.x, tid = threadIdx.x;
    int vbase = b << 7;
    if (vbase >= N) return;
    for (int i = tid; i < NPB * 16; i += BLK) acc[i] = 0.f;
    __syncthreads();
    unsigned s0 = binBase[b], n = binCnt[b];
    int q = tid & 3;
    for (unsigned i = tid >> 2; i < n; i += (BLK >> 2)) {
        unsigned p = packed[s0 + i];
        unsigned s = p & 0x1FFFFu, ld = p >> 17;
        float4 val = ((const float4*)h1s)[s * 4 + q];
        float* a = acc + ld * 16 + q * 4;
        atomicAdd(a + 0, val.x);
        atomicAdd(a + 1, val.y);
        atomicAdd(a + 2, val.z);
        atomicAdd(a + 3, val.w);
    }
    __syncthreads();
    for (int i = tid; i < NPB * 16; i += BLK) {
        int lv = i >> 4, c = i & 15;
        int v = vbase + lv;
        if (v < N) {
            float dv = dinv[v];
            float val = fmaxf(fmaf(h1s[(size_t)v * 16 + c] + acc[i], dv, b1[c]), 0.f) * dv;
            z1s[(size_t)v * 16 + c] = val;
        }
    }
}

// Bin-local aggregation of z1s, fused 16x64 GEMM + log_softmax epilogue.
__global__ __launch_bounds__(BLK)
void bin_agg2_k(const unsigned* __restrict__ packed,
                const unsigned* __restrict__ binBase,
                const unsigned* __restrict__ binCnt,
                const float* __restrict__ z1s, const float* __restrict__ dinv,
                const float* __restrict__ W2, const float* __restrict__ b2,
                float* __restrict__ out, int N) {
    __shared__ float acc[NPB * 16];     // 8 KB
    __shared__ float w2s[1024];         // 4 KB
    __shared__ float b2s[64];
    int b = blockIdx.x, tid = threadIdx.x;
    int vbase = b << 7;
    if (vbase >= N) return;
    for (int i = tid; i < NPB * 16; i += BLK) acc[i] = 0.f;
    for (int i = tid; i < 1024; i += BLK) w2s[i] = W2[i];
    if (tid < 64) b2s[tid] = b2[tid];
    __syncthreads();
    unsigned s0 = binBase[b], n = binCnt[b];
    int q = tid & 3;
    for (unsigned i = tid >> 2; i < n; i += (BLK >> 2)) {
        unsigned p = packed[s0 + i];
        unsigned s = p & 0x1FFFFu, ld = p >> 17;
        float4 val = ((const float4*)z1s)[s * 4 + q];
        float* a = acc + ld * 16 + q * 4;
        atomicAdd(a + 0, val.x);
        atomicAdd(a + 1, val.y);
        atomicAdd(a + 2, val.z);
        atomicAdd(a + 3, val.w);
    }
    __syncthreads();
    int lane = tid & 63;
    for (int lv = tid >> 6; lv < NPB; lv += 4) {
        int v = vbase + lv;
        if (v >= N) break;
        float dv = dinv[v];
        float w = (z1s[(size_t)v * 16 + (lane & 15)] + acc[lv * 16 + (lane & 15)]) * dv;
        float a = b2s[lane];
#pragma unroll
        for (int k = 0; k < 16; ++k)
            a = fmaf(__shfl(w, k, 64), w2s[k * 64 + lane], a);
        float m = a;
#pragma unroll
        for (int off = 32; off; off >>= 1) m = fmaxf(m, __shfl_xor(m, off, 64));
        float p = __expf(a - m);
#pragma unroll
        for (int off = 32; off; off >>= 1) p += __shfl_xor(p, off, 64);
        out[(size_t)v * 64 + lane] = a - m - __logf(p);
    }
}

extern "C" void kernel_launch(void* const* d_in, const int* in_sizes, int n_in,
                              void* d_out, int out_size, void* d_ws, size_t ws_size,
                              hipStream_t stream) {
    const float* x  = (const float*)d_in[0];
    const int*   ei = (const int*)d_in[1];
    const float* W1 = (const float*)d_in[2];
    const float* b1 = (const float*)d_in[3];
    const float* W2 = (const float*)d_in[4];
    const float* b2 = (const float*)d_in[5];
    float* out = (float*)d_out;

    int hid   = in_sizes[3];                   // 16
    int in_ch = in_sizes[2] / hid;             // 512
    int E     = in_sizes[1] / 2;               // 3.2M
    int N     = in_sizes[0] / in_ch;           // 100000
    const int* src = ei;
    const int* dst = ei + E;
    int nbins = (N + NPB - 1) / NPB;           // 782

    char* w = (char*)d_ws;
    size_t off = 0;
    auto alloc = [&](size_t bytes) -> void* {
        void* p = w + off;
        off += (bytes + 255) & ~(size_t)255;
        return p;
    };
    unsigned* binCnt    = (unsigned*)alloc((size_t)nbins * 4);
    unsigned* binBase   = (unsigned*)alloc((size_t)nbins * 4);
    unsigned* binCursor = (unsigned*)alloc((size_t)nbins * 4);
    unsigned* packed    = (unsigned*)alloc((size_t)E * 4);
    float*    dinv      = (float*)alloc((size_t)N * 4);
    float*    h1s       = (float*)alloc((size_t)N * 64);
    float*    z1s       = (float*)alloc((size_t)N * 64);

    int nchunks = (E + CHUNK - 1) / CHUNK;

    hipMemsetAsync(binCnt, 0, (size_t)nbins * 4, stream);
    bin_count_k<<<nchunks, BLK, 0, stream>>>(dst, E, nbins, binCnt);
    scan_k<<<1, 1024, 0, stream>>>(binCnt, nbins, binBase, binCursor);
    scatter_k<<<nchunks, BLK, 0, stream>>>(src, dst, E, nbins, binCursor, packed);
    bin_dinv_k<<<nbins, BLK, 0, stream>>>(packed, binBase, binCnt, dinv, N);
    gemm1_k<<<(N * 16 + BLK - 1) / BLK, BLK, 0, stream>>>(x, W1, dinv, h1s, N);
    bin_agg1_k<<<nbins, BLK, 0, stream>>>(packed, binBase, binCnt, h1s, dinv, b1, z1s, N);
    bin_agg2_k<<<nbins, BLK, 0, stream>>>(packed, binBase, binCnt, z1s, dinv, W2, b2, out, N);
}

// Round 3
// 1219.229 us; speedup vs baseline: 1.5751x; 1.0732x over previous
//
#include <hip/hip_runtime.h>
#include <hip/hip_bf16.h>

#define BLK 256
#define CHUNK 16384         // edges per binning block
#define NPB 32              // nodes per bin (LDS accum = 32*16*4 = 2KB)
#define NPB_SHIFT 5
#define MAXBINS 3328        // >= ceil(100000/32)=3125
#define SRCMASK 0x1FFFFu    // 17-bit src id
#define LDSHIFT 17

// ---------------------------------------------------------------------------
// GCN, atomic-free aggregation via destination binning (small bins for TLP):
//   bin edges by dst>>5 once (count/scan/scatter, packed src|ldst<<17)
//   dinv from binned edges (LDS counters)
//   h1s = (x@W1)*dinv
//   bin_agg1: LDS-accumulate h1s[src] per bin; fused epilogue ->
//             z1s = relu((h1s + agg)*dinv + b1)*dinv
//   bin_agg2: LDS-accumulate z1s[src] per bin; fused epilogue ->
//             out = log_softmax(((z1s + agg)*dinv) @ W2 + b2)
// ---------------------------------------------------------------------------

__global__ __launch_bounds__(BLK)
void bin_count_k(const int* __restrict__ dst, int E,
                 int nbins, unsigned* __restrict__ binCnt) {
    __shared__ unsigned h[MAXBINS];
    for (int i = threadIdx.x; i < nbins; i += BLK) h[i] = 0u;
    __syncthreads();
    int base = blockIdx.x * CHUNK;
    int end  = min(base + CHUNK, E);
    for (int e = base + threadIdx.x; e < end; e += BLK)
        atomicAdd(&h[dst[e] >> NPB_SHIFT], 1u);
    __syncthreads();
    for (int i = threadIdx.x; i < nbins; i += BLK)
        if (h[i]) atomicAdd(&binCnt[i], h[i]);
}

// single block, 1024 threads, looped scan with carry (handles nbins > 1024)
__global__ __launch_bounds__(1024)
void scan_k(const unsigned* __restrict__ binCnt, int nbins,
            unsigned* __restrict__ binBase, unsigned* __restrict__ binCursor) {
    __shared__ unsigned s[1024];
    __shared__ unsigned carry;
    int t = threadIdx.x;
    if (t == 0) carry = 0u;
    __syncthreads();
    for (int base = 0; base < nbins; base += 1024) {
        unsigned v = (base + t < nbins) ? binCnt[base + t] : 0u;
        s[t] = v;
        __syncthreads();
        for (int off = 1; off < 1024; off <<= 1) {
            unsigned add = (t >= off) ? s[t - off] : 0u;
            __syncthreads();
            s[t] += add;
            __syncthreads();
        }
        unsigned c0 = carry;
        if (base + t < nbins) {
            unsigned excl = c0 + s[t] - v;
            binBase[base + t]   = excl;
            binCursor[base + t] = excl;
        }
        __syncthreads();
        if (t == 0) carry += s[1023];
        __syncthreads();
    }
}

__global__ __launch_bounds__(BLK)
void scatter_k(const int* __restrict__ src, const int* __restrict__ dst, int E,
               int nbins, unsigned* __restrict__ binCursor,
               unsigned* __restrict__ packed) {
    __shared__ unsigned h[MAXBINS];
    __shared__ unsigned cur[MAXBINS];
    for (int i = threadIdx.x; i < nbins; i += BLK) h[i] = 0u;
    __syncthreads();
    int base = blockIdx.x * CHUNK;
    int end  = min(base + CHUNK, E);
    for (int e = base + threadIdx.x; e < end; e += BLK)
        atomicAdd(&h[dst[e] >> NPB_SHIFT], 1u);
    __syncthreads();
    for (int i = threadIdx.x; i < nbins; i += BLK)
        cur[i] = h[i] ? atomicAdd(&binCursor[i], h[i]) : 0u;
    __syncthreads();
    for (int e = base + threadIdx.x; e < end; e += BLK) {
        int d = dst[e];
        unsigned pos = atomicAdd(&cur[d >> NPB_SHIFT], 1u);
        packed[pos] = (unsigned)src[e] | ((unsigned)(d & (NPB - 1)) << LDSHIFT);
    }
}

__global__ __launch_bounds__(BLK)
void bin_dinv_k(const unsigned* __restrict__ packed,
                const unsigned* __restrict__ binBase,
                const unsigned* __restrict__ binCnt,
                float* __restrict__ dinv, int N) {
    __shared__ unsigned cnt[NPB];
    int b = blockIdx.x, tid = threadIdx.x;
    int vbase = b << NPB_SHIFT;
    if (vbase >= N) return;
    if (tid < NPB) cnt[tid] = 0u;
    __syncthreads();
    unsigned s0 = binBase[b], n = binCnt[b];
    for (unsigned i = tid; i < n; i += BLK)
        atomicAdd(&cnt[packed[s0 + i] >> LDSHIFT], 1u);
    __syncthreads();
    int v = vbase + tid;
    if (tid < NPB && v < N)
        dinv[v] = rsqrtf((float)cnt[tid] + 1.0f);
}

// h1s[v][c] = (x[v] @ W1[:,c]) * dinv[v]; 16 threads per node row.
__global__ __launch_bounds__(BLK)
void gemm1_k(const float* __restrict__ x, const float* __restrict__ W1,
             const float* __restrict__ dinv, float* __restrict__ h1s, int N) {
    int t = blockIdx.x * BLK + threadIdx.x;
    int v = t >> 4, c = t & 15;
    if (v >= N) return;
    const float4* xr = (const float4*)(x + (size_t)v * 512);
    float acc = 0.f;
#pragma unroll 8
    for (int i = 0; i < 128; ++i) {
        float4 a = xr[i];
        const float* wr = W1 + i * 64 + c;
        acc = fmaf(a.x, wr[0],  acc);
        acc = fmaf(a.y, wr[16], acc);
        acc = fmaf(a.z, wr[32], acc);
        acc = fmaf(a.w, wr[48], acc);
    }
    h1s[t] = acc * dinv[v];
}

// Bin-local aggregation of h1s into LDS, fused relu/bias epilogue -> z1s.
__global__ __launch_bounds__(BLK)
void bin_agg1_k(const unsigned* __restrict__ packed,
                const unsigned* __restrict__ binBase,
                const unsigned* __restrict__ binCnt,
                const float* __restrict__ h1s, const float* __restrict__ dinv,
                const float* __restrict__ b1, float* __restrict__ z1s, int N) {
    __shared__ float acc[NPB * 16];     // 2 KB
    int b = blockIdx.x, tid = threadIdx.x;
    int vbase = b << NPB_SHIFT;
    if (vbase >= N) return;
    for (int i = tid; i < NPB * 16; i += BLK) acc[i] = 0.f;
    __syncthreads();
    unsigned s0 = binBase[b], n = binCnt[b];
    int q = tid & 3;
    const unsigned step = BLK >> 2;
    unsigned i = tid >> 2;
    for (; i + step < n; i += 2 * step) {       // unroll x2 for ILP
        unsigned p1 = packed[s0 + i];
        unsigned p2 = packed[s0 + i + step];
        float4 v1 = ((const float4*)h1s)[(p1 & SRCMASK) * 4 + q];
        float4 v2 = ((const float4*)h1s)[(p2 & SRCMASK) * 4 + q];
        float* a1 = acc + (p1 >> LDSHIFT) * 16 + q * 4;
        atomicAdd(a1 + 0, v1.x); atomicAdd(a1 + 1, v1.y);
        atomicAdd(a1 + 2, v1.z); atomicAdd(a1 + 3, v1.w);
        float* a2 = acc + (p2 >> LDSHIFT) * 16 + q * 4;
        atomicAdd(a2 + 0, v2.x); atomicAdd(a2 + 1, v2.y);
        atomicAdd(a2 + 2, v2.z); atomicAdd(a2 + 3, v2.w);
    }
    for (; i < n; i += step) {
        unsigned p = packed[s0 + i];
        float4 val = ((const float4*)h1s)[(p & SRCMASK) * 4 + q];
        float* a = acc + (p >> LDSHIFT) * 16 + q * 4;
        atomicAdd(a + 0, val.x); atomicAdd(a + 1, val.y);
        atomicAdd(a + 2, val.z); atomicAdd(a + 3, val.w);
    }
    __syncthreads();
    for (int i2 = tid; i2 < NPB * 16; i2 += BLK) {
        int lv = i2 >> 4, c = i2 & 15;
        int v = vbase + lv;
        if (v < N) {
            float dv = dinv[v];
            float val = fmaxf(fmaf(h1s[(size_t)v * 16 + c] + acc[i2], dv, b1[c]), 0.f) * dv;
            z1s[(size_t)v * 16 + c] = val;
        }
    }
}

// Bin-local aggregation of z1s, fused 16x64 GEMM + log_softmax epilogue.
__global__ __launch_bounds__(BLK)
void bin_agg2_k(const unsigned* __restrict__ packed,
                const unsigned* __restrict__ binBase,
                const unsigned* __restrict__ binCnt,
                const float* __restrict__ z1s, const float* __restrict__ dinv,
                const float* __restrict__ W2, const float* __restrict__ b2,
                float* __restrict__ out, int N) {
    __shared__ float acc[NPB * 16];     // 2 KB
    __shared__ float w2s[1024];         // 4 KB
    __shared__ float b2s[64];
    int b = blockIdx.x, tid = threadIdx.x;
    int vbase = b << NPB_SHIFT;
    if (vbase >= N) return;
    for (int i = tid; i < NPB * 16; i += BLK) acc[i] = 0.f;
    for (int i = tid; i < 1024; i += BLK) w2s[i] = W2[i];
    if (tid < 64) b2s[tid] = b2[tid];
    __syncthreads();
    unsigned s0 = binBase[b], n = binCnt[b];
    int q = tid & 3;
    const unsigned step = BLK >> 2;
    unsigned i = tid >> 2;
    for (; i + step < n; i += 2 * step) {       // unroll x2 for ILP
        unsigned p1 = packed[s0 + i];
        unsigned p2 = packed[s0 + i + step];
        float4 v1 = ((const float4*)z1s)[(p1 & SRCMASK) * 4 + q];
        float4 v2 = ((const float4*)z1s)[(p2 & SRCMASK) * 4 + q];
        float* a1 = acc + (p1 >> LDSHIFT) * 16 + q * 4;
        atomicAdd(a1 + 0, v1.x); atomicAdd(a1 + 1, v1.y);
        atomicAdd(a1 + 2, v1.z); atomicAdd(a1 + 3, v1.w);
        float* a2 = acc + (p2 >> LDSHIFT) * 16 + q * 4;
        atomicAdd(a2 + 0, v2.x); atomicAdd(a2 + 1, v2.y);
        atomicAdd(a2 + 2, v2.z); atomicAdd(a2 + 3, v2.w);
    }
    for (; i < n; i += step) {
        unsigned p = packed[s0 + i];
        float4 val = ((const float4*)z1s)[(p & SRCMASK) * 4 + q];
        float* a = acc + (p >> LDSHIFT) * 16 + q * 4;
        atomicAdd(a + 0, val.x); atomicAdd(a + 1, val.y);
        atomicAdd(a + 2, val.z); atomicAdd(a + 3, val.w);
    }
    __syncthreads();
    int lane = tid & 63;
    for (int lv = tid >> 6; lv < NPB; lv += 4) {
        int v = vbase + lv;
        if (v >= N) break;
        float dv = dinv[v];
        float w = (z1s[(size_t)v * 16 + (lane & 15)] + acc[lv * 16 + (lane & 15)]) * dv;
        float a = b2s[lane];
#pragma unroll
        for (int k = 0; k < 16; ++k)
            a = fmaf(__shfl(w, k, 64), w2s[k * 64 + lane], a);
        float m = a;
#pragma unroll
        for (int off = 32; off; off >>= 1) m = fmaxf(m, __shfl_xor(m, off, 64));
        float p = __expf(a - m);
#pragma unroll
        for (int off = 32; off; off >>= 1) p += __shfl_xor(p, off, 64);
        out[(size_t)v * 64 + lane] = a - m - __logf(p);
    }
}

extern "C" void kernel_launch(void* const* d_in, const int* in_sizes, int n_in,
                              void* d_out, int out_size, void* d_ws, size_t ws_size,
                              hipStream_t stream) {
    const float* x  = (const float*)d_in[0];
    const int*   ei = (const int*)d_in[1];
    const float* W1 = (const float*)d_in[2];
    const float* b1 = (const float*)d_in[3];
    const float* W2 = (const float*)d_in[4];
    const float* b2 = (const float*)d_in[5];
    float* out = (float*)d_out;

    int hid   = in_sizes[3];                   // 16
    int in_ch = in_sizes[2] / hid;             // 512
    int E     = in_sizes[1] / 2;               // 3.2M
    int N     = in_sizes[0] / in_ch;           // 100000
    const int* src = ei;
    const int* dst = ei + E;
    int nbins = (N + NPB - 1) / NPB;           // 3125

    char* w = (char*)d_ws;
    size_t off = 0;
    auto alloc = [&](size_t bytes) -> void* {
        void* p = w + off;
        off += (bytes + 255) & ~(size_t)255;
        return p;
    };
    unsigned* binCnt    = (unsigned*)alloc((size_t)nbins * 4);
    unsigned* binBase   = (unsigned*)alloc((size_t)nbins * 4);
    unsigned* binCursor = (unsigned*)alloc((size_t)nbins * 4);
    unsigned* packed    = (unsigned*)alloc((size_t)E * 4);
    float*    dinv      = (float*)alloc((size_t)N * 4);
    float*    h1s       = (float*)alloc((size_t)N * 64);
    float*    z1s       = (float*)alloc((size_t)N * 64);

    int nchunks = (E + CHUNK - 1) / CHUNK;

    hipMemsetAsync(binCnt, 0, (size_t)nbins * 4, stream);
    bin_count_k<<<nchunks, BLK, 0, stream>>>(dst, E, nbins, binCnt);
    scan_k<<<1, 1024, 0, stream>>>(binCnt, nbins, binBase, binCursor);
    scatter_k<<<nchunks, BLK, 0, stream>>>(src, dst, E, nbins, binCursor, packed);
    bin_dinv_k<<<nbins, BLK, 0, stream>>>(packed, binBase, binCnt, dinv, N);
    gemm1_k<<<(N * 16 + BLK - 1) / BLK, BLK, 0, stream>>>(x, W1, dinv, h1s, N);
    bin_agg1_k<<<nbins, BLK, 0, stream>>>(packed, binBase, binCnt, h1s, dinv, b1, z1s, N);
    bin_agg2_k<<<nbins, BLK, 0, stream>>>(packed, binBase, binCnt, z1s, dinv, W2, b2, out, N);
}